// Round 2
// baseline (357.071 us; speedup 1.0000x reference)
//
#include <hip/hip_runtime.h>
#include <hip/hip_bf16.h>
#include <cstdint>

typedef unsigned short u16;
typedef unsigned int u32;
typedef __bf16 bf16x8 __attribute__((ext_vector_type(8)));
typedef float f32x4 __attribute__((ext_vector_type(4)));

#define BDIM 2
#define TDIM 2048
#define HIDDIM 2048
#define NHEAD 16
#define NKVH 4
#define HD 128
#define MROWS (BDIM*TDIM)     /* 4096 */
#define NQKV 3072
#define KDIM 2048

#define MFMA16(a,b,c) __builtin_amdgcn_mfma_f32_16x16x32_bf16((a),(b),(c),0,0,0)

__device__ __forceinline__ u16 f2bf(float f) {
    __bf16 h = (__bf16)f;
    return __builtin_bit_cast(u16, h);
}
__device__ __forceinline__ float bf2f(u32 u) {
    u <<= 16;
    return __builtin_bit_cast(float, u);
}
__device__ __forceinline__ void gld16(const void* g, void* l) {
    __builtin_amdgcn_global_load_lds(
        (const __attribute__((address_space(1))) u32*)g,
        (__attribute__((address_space(3))) u32*)l, 16, 0, 0);
}

// ---------------- fused prep: x->bf16 convert + 4 weight transposes ----------------
// grid layout: [0,4096) cvt_x | [4096,8192) Wq | [8192,9216) Wk
//              [9216,10240) Wv | [10240,14336) Wo
__global__ __launch_bounds__(256) void prep_kernel(const float* __restrict__ x,
                                                   u16* __restrict__ xb,
                                                   const float* __restrict__ Wq,
                                                   const float* __restrict__ Wk,
                                                   const float* __restrict__ Wv,
                                                   const float* __restrict__ Wo,
                                                   u16* __restrict__ Wqkvt,
                                                   u16* __restrict__ Wot) {
    __shared__ float tile[32][33];
    const int bi = blockIdx.x;
    const int tid = threadIdx.x;
    if (bi < 4096) {
        size_t i = ((size_t)bi * 256 + tid) * 8;
        float4 a = *(const float4*)(x + i);
        float4 b = *(const float4*)(x + i + 4);
        uint4 v;
        v.x = (u32)f2bf(a.x) | ((u32)f2bf(a.y) << 16);
        v.y = (u32)f2bf(a.z) | ((u32)f2bf(a.w) << 16);
        v.z = (u32)f2bf(b.x) | ((u32)f2bf(b.y) << 16);
        v.w = (u32)f2bf(b.z) | ((u32)f2bf(b.w) << 16);
        *(uint4*)(xb + i) = v;
        return;
    }
    const float* src;
    u16* dst;
    int N, n0, k0;
    if (bi < 8192) {
        int t = bi - 4096; src = Wq; dst = Wqkvt; N = 2048;
        n0 = (t & 63) * 32; k0 = (t >> 6) * 32;
    } else if (bi < 9216) {
        int t = bi - 8192; src = Wk; dst = Wqkvt + (size_t)2048 * KDIM; N = 512;
        n0 = (t & 15) * 32; k0 = (t >> 4) * 32;
    } else if (bi < 10240) {
        int t = bi - 9216; src = Wv; dst = Wqkvt + (size_t)2560 * KDIM; N = 512;
        n0 = (t & 15) * 32; k0 = (t >> 4) * 32;
    } else {
        int t = bi - 10240; src = Wo; dst = Wot; N = 2048;
        n0 = (t & 63) * 32; k0 = (t >> 6) * 32;
    }
    const int tx = tid & 31, ty = tid >> 5;   // 32 x 8
#pragma unroll
    for (int r = 0; r < 4; r++)
        tile[ty + 8*r][tx] = src[(size_t)(k0 + ty + 8*r) * N + n0 + tx];
    __syncthreads();
#pragma unroll
    for (int r = 0; r < 4; r++)
        dst[(size_t)(n0 + ty + 8*r) * KDIM + k0 + tx] = f2bf(tile[tx][ty + 8*r]);
}

// ---------------- GEMM: C[m][n] = sum_k A[m][k] * Bt[n][k] ----------------
template<int OUT_BF16>
__global__ void __launch_bounds__(256, 2) gemm_bt(const u16* __restrict__ A,
                                                  const u16* __restrict__ Bt,
                                                  void* __restrict__ C, int ldc) {
    __shared__ __align__(16) u16 Al[128 * 32];
    __shared__ __align__(16) u16 Bl[128 * 32];
    const int tid = threadIdx.x;
    const int lane = tid & 63;
    const int w = tid >> 6;
    const int wm = (w & 1) * 64;
    const int wn = (w >> 1) * 64;
    const int quad = lane >> 4;
    const int l15 = lane & 15;
    const size_t bm = (size_t)blockIdx.x * 128;
    const size_t bn = (size_t)blockIdx.y * 128;

    const int srow = lane >> 2;
    const int kq = (lane & 3) ^ ((lane >> 3) & 3);
    const int i0 = 2 * w, i1 = 2 * w + 1;

    const u16* ga0 = A + (bm + i0*16 + srow) * KDIM + kq * 8;
    const u16* ga1 = A + (bm + i1*16 + srow) * KDIM + kq * 8;
    const u16* gb0 = Bt + (bn + i0*16 + srow) * KDIM + kq * 8;
    const u16* gb1 = Bt + (bn + i1*16 + srow) * KDIM + kq * 8;

    const int swz = ((quad ^ ((l15 >> 1) & 3)) << 3);
    int aoff[4], boff[4];
#pragma unroll
    for (int t = 0; t < 4; t++) {
        aoff[t] = (wm + t*16 + l15) * 32 + swz;
        boff[t] = (wn + t*16 + l15) * 32 + swz;
    }

    f32x4 acc[4][4] = {};

    for (int kt = 0; kt < KDIM / 32; kt++) {
        gld16(ga0 + kt*32, &Al[i0 * 512]);
        gld16(ga1 + kt*32, &Al[i1 * 512]);
        gld16(gb0 + kt*32, &Bl[i0 * 512]);
        gld16(gb1 + kt*32, &Bl[i1 * 512]);
        __syncthreads();
        bf16x8 af[4], bfv[4];
#pragma unroll
        for (int t = 0; t < 4; t++) {
            af[t]  = *(const bf16x8*)&Al[aoff[t]];
            bfv[t] = *(const bf16x8*)&Bl[boff[t]];
        }
#pragma unroll
        for (int mt = 0; mt < 4; mt++)
#pragma unroll
            for (int nt = 0; nt < 4; nt++)
                acc[mt][nt] = MFMA16(af[mt], bfv[nt], acc[mt][nt]);
        __syncthreads();
    }

#pragma unroll
    for (int mt = 0; mt < 4; mt++) {
        size_t m0 = bm + wm + mt*16 + quad*4;
#pragma unroll
        for (int nt = 0; nt < 4; nt++) {
            size_t n = bn + wn + nt*16 + l15;
#pragma unroll
            for (int r = 0; r < 4; r++) {
                if (OUT_BF16)
                    ((u16*)C)[(m0 + r) * (size_t)ldc + n] = f2bf(acc[mt][nt][r]);
                else
                    ((float*)C)[(m0 + r) * (size_t)ldc + n] = acc[mt][nt][r];
            }
        }
    }
}

// ---------------- rotary (in-place on Q and K parts of QKV), Q gets scale folded ----------------
__global__ __launch_bounds__(256) void rotary_kernel(u16* __restrict__ QKV,
                                                     const float* __restrict__ cosT,
                                                     const float* __restrict__ sinT) {
    int i = blockIdx.x * 256 + threadIdx.x;   // < 4096*320
    int m = i / 320;
    int rem = i - m * 320;
    int head = rem >> 4;
    int d0 = (rem & 15) << 2;                 // 0..60
    int t = m & (TDIM - 1);
    int col;
    float sc;
    if (head < NHEAD) {
        col = head * HD + d0;
        sc = 0.08838834764831845f * 1.4426950408889634f; // 1/sqrt(128) * log2(e)
    } else {
        col = HIDDIM + (head - NHEAD) * HD + d0;
        sc = 1.0f;
    }
    u16* p0 = QKV + (size_t)m * NQKV + col;
    u16* p1 = p0 + 64;
    float4 cv = *(const float4*)(cosT + t * HD + d0);
    float4 sv = *(const float4*)(sinT + t * HD + d0);
    uint2 qa = *(const uint2*)p0;
    uint2 qb = *(const uint2*)p1;
    float f0[4] = { bf2f(qa.x & 0xffffu), bf2f(qa.x >> 16), bf2f(qa.y & 0xffffu), bf2f(qa.y >> 16) };
    float f1[4] = { bf2f(qb.x & 0xffffu), bf2f(qb.x >> 16), bf2f(qb.y & 0xffffu), bf2f(qb.y >> 16) };
    float c[4] = { cv.x, cv.y, cv.z, cv.w };
    float s[4] = { sv.x, sv.y, sv.z, sv.w };
    u16 o0[4], o1[4];
#pragma unroll
    for (int k = 0; k < 4; k++) {
        o0[k] = f2bf((f0[k] * c[k] - f1[k] * s[k]) * sc);
        o1[k] = f2bf((f1[k] * c[k] + f0[k] * s[k]) * sc);
    }
    uint2 w0, w1;
    w0.x = (u32)o0[0] | ((u32)o0[1] << 16);
    w0.y = (u32)o0[2] | ((u32)o0[3] << 16);
    w1.x = (u32)o1[0] | ((u32)o1[1] << 16);
    w1.y = (u32)o1[2] | ((u32)o1[3] << 16);
    *(uint2*)p0 = w0;
    *(uint2*)p1 = w1;
}

// ---------------- flash attention, causal, GQA ----------------
// Swapped-operand design: S^T = mfma(K,Q) so each lane owns ONE q-row (q = l15,
// replicated over quads). Softmax stats fully lane-local after two __shfl_xor
// reduces (16, 32). PV uses the ZERO-SHUFFLE trick: the MFMA contraction only
// needs A and B to agree on the (quad,elem)->k mapping, so the B-fragment is
// the lane's OWN 8 P-values (h(quad,b) = kt*32 + (b>=4)*16 + quad*4 + (b&3)),
// and Vt is stored with bit-permuted columns c(s) (bit4 <-> bits3:2) so a
// single b128 read delivers V with the SAME mapping. No P LDS buffer at all.
// O^T = mfma(V^T, P^T): alpha / 1/l rescales are lane-local scalars.
// LDS = 32K (K dbuf) + 18K (Vt, LV=72) = 51.2 KB -> 3 blocks/CU.
// Grid: 1024 single-Q-tile blocks, longest tile first (qt = 31 - blockIdx.x).
__global__ void __launch_bounds__(256, 3) attn_kernel(const u16* __restrict__ QKV,
                                                      u16* __restrict__ AO) {
    constexpr int LV = 72;   // Vt row stride
    __shared__ __align__(16) u16 Kl[2][64 * 128];  // double-buffered K tile
    __shared__ __align__(16) u16 Vt[128 * LV];     // V transposed [d][c(s)]

    const int qt = 31 - blockIdx.x;  // Q-tile (64 rows); longest blocks dispatch first
    const int h  = blockIdx.y;
    const int b  = blockIdx.z;
    const int kh = h >> 2;
    const int tid = threadIdx.x;
    const int lane = tid & 63;
    const int w = tid >> 6;
    const int quad = lane >> 4;
    const int l15 = lane & 15;

    const size_t rowbase = (size_t)b * TDIM;
    const u16* Qb = QKV + rowbase * NQKV + h * HD;
    const u16* Kb = QKV + rowbase * NQKV + HIDDIM + kh * HD;
    const u16* Vb = Kb + NKVH * HD;

    // K staging: instr i stages rows w*16+i*4..+3; chunk swizzle c ^= (row&7)
    int krow[4], kgch[4];
#pragma unroll
    for (int i = 0; i < 4; i++) {
        krow[i] = w*16 + i*4 + quad;
        kgch[i] = l15 ^ (krow[i] & 7);
    }
    // V staging lane mapping: sp (s-pair), dch (d-chunk of 8)
    const int sp0 = tid & 31, dch0 = tid >> 5, dch1 = dch0 + 8;
    // bit-permuted Vt column: swap s-bit4 with s-bits3:2  (c(s+1)=c(s)+1, s even)
    const int s0v = sp0 * 2;
    const int ccv = (s0v & ~0x1C) | ((s0v & 0x0C) << 1) | ((s0v & 0x10) >> 2);

    // Q fragments: wave w owns rows qt*64 + w*16 .. +15 (pre-scaled by 1/sqrt(d)*log2e)
    bf16x8 qf[4];
    {
        const u16* qr = Qb + (size_t)(qt*64 + w*16 + l15) * NQKV;
#pragma unroll
        for (int kt = 0; kt < 4; kt++)
            qf[kt] = *(const bf16x8*)(qr + kt*32 + quad*8);
    }
    f32x4 O[8] = {};          // O^T: O[nt][r] = O^T[d=nt*16+quad*4+r][q=w*16+l15]
    float mrun = -1e30f, lrun = 0.0f;

    // ---- prologue: prefetch K(0) -> Kl[0], V(0) -> regs ----
#pragma unroll
    for (int i = 0; i < 4; i++)
        gld16(Kb + (size_t)krow[i] * NQKV + kgch[i]*8, &Kl[0][(w*16 + i*4) * 128]);
    uint4 vr0a, vr0b, vr1a, vr1b;
    {
        const u16* g0 = Vb + (size_t)s0v * NQKV + dch0*8;
        vr0a = *(const uint4*)g0;
        vr0b = *(const uint4*)(g0 + NQKV);
        const u16* g1 = Vb + (size_t)s0v * NQKV + dch1*8;
        vr1a = *(const uint4*)g1;
        vr1b = *(const uint4*)(g1 + NQKV);
    }

#pragma unroll 1
    for (int j = 0; j <= qt; j++) {
        // ---- write V(j) regs -> Vt at permuted columns (bank-uniform, free) ----
        {
            u32 ra[4] = { vr0a.x, vr0a.y, vr0a.z, vr0a.w };
            u32 rb[4] = { vr0b.x, vr0b.y, vr0b.z, vr0b.w };
            int d0 = dch0*8;
#pragma unroll
            for (int k2 = 0; k2 < 4; k2++) {
                u32 lo = (ra[k2] & 0xffffu) | (rb[k2] << 16);
                u32 hi = (ra[k2] >> 16) | (rb[k2] & 0xffff0000u);
                *(u32*)&Vt[(d0 + 2*k2)     * LV + ccv] = lo;
                *(u32*)&Vt[(d0 + 2*k2 + 1) * LV + ccv] = hi;
            }
            u32 rc[4] = { vr1a.x, vr1a.y, vr1a.z, vr1a.w };
            u32 rd[4] = { vr1b.x, vr1b.y, vr1b.z, vr1b.w };
            d0 = dch1*8;
#pragma unroll
            for (int k2 = 0; k2 < 4; k2++) {
                u32 lo = (rc[k2] & 0xffffu) | (rd[k2] << 16);
                u32 hi = (rc[k2] >> 16) | (rd[k2] & 0xffff0000u);
                *(u32*)&Vt[(d0 + 2*k2)     * LV + ccv] = lo;
                *(u32*)&Vt[(d0 + 2*k2 + 1) * LV + ccv] = hi;
            }
        }
        __syncthreads();   // [A] K(j) landed (vmcnt drain), Vt visible

        // ---- prefetch K(j+1), V(j+1) (hidden behind this iter's compute) ----
        if (j < qt) {
            const u16* Kbn = Kb + (size_t)(j+1) * 64 * NQKV;
            u16* kl = Kl[(j+1) & 1];
#pragma unroll
            for (int i = 0; i < 4; i++)
                gld16(Kbn + (size_t)krow[i] * NQKV + kgch[i]*8, &kl[(w*16 + i*4) * 128]);
            const u16* Vbn = Vb + (size_t)(j+1) * 64 * NQKV;
            const u16* g0 = Vbn + (size_t)s0v * NQKV + dch0*8;
            vr0a = *(const uint4*)g0;
            vr0b = *(const uint4*)(g0 + NQKV);
            const u16* g1 = Vbn + (size_t)s0v * NQKV + dch1*8;
            vr1a = *(const uint4*)g1;
            vr1b = *(const uint4*)(g1 + NQKV);
        }

        // ---- S^T = mfma(K, Q): S[nt][r] = scores[q=w*16+l15][s=nt*16+quad*4+r] ----
        const u16* kl = Kl[j & 1];
        f32x4 S[4] = {};
#pragma unroll
        for (int kt = 0; kt < 4; kt++) {
            int p = (kt*4 + quad) ^ (l15 & 7);
#pragma unroll
            for (int nt = 0; nt < 4; nt++) {
                bf16x8 afr = *(const bf16x8*)&kl[(nt*16 + l15)*128 + p*8];
                S[nt] = MFMA16(afr, qf[kt], S[nt]);
            }
        }

        // ---- causal mask: only the diagonal tile is boundary ----
        if (j == qt) {
            const int qloc = w*16 + l15;
#pragma unroll
            for (int nt = 0; nt < 4; nt++) {
                const int sb = nt*16 + quad*4;
#pragma unroll
                for (int r = 0; r < 4; r++)
                    if (sb + r > qloc) S[nt][r] = -1e30f;
            }
        }

        // ---- online softmax: lane owns row q = w*16+l15 (stats shared by quads) ----
        {
            float mx0 = fmaxf(fmaxf(S[0][0], S[0][1]), fmaxf(S[0][2], S[0][3]));
            float mx1 = fmaxf(fmaxf(S[1][0], S[1][1]), fmaxf(S[1][2], S[1][3]));
            float mx2 = fmaxf(fmaxf(S[2][0], S[2][1]), fmaxf(S[2][2], S[2][3]));
            float mx3 = fmaxf(fmaxf(S[3][0], S[3][1]), fmaxf(S[3][2], S[3][3]));
            float mx = fmaxf(fmaxf(mx0, mx1), fmaxf(mx2, mx3));
            mx = fmaxf(mx, __shfl_xor(mx, 16, 64));   // across quad pairs
            mx = fmaxf(mx, __shfl_xor(mx, 32, 64));   // across halves
            float mnew = fmaxf(mrun, mx);
            float alpha = __builtin_amdgcn_exp2f(mrun - mnew);
            mrun = mnew;
            float rs = 0.0f;
#pragma unroll
            for (int nt = 0; nt < 4; nt++)
#pragma unroll
                for (int r = 0; r < 4; r++) {
                    float pv = __builtin_amdgcn_exp2f(S[nt][r] - mnew);
                    S[nt][r] = pv;
                    rs += pv;
                }
            rs += __shfl_xor(rs, 16, 64);
            rs += __shfl_xor(rs, 32, 64);
            lrun = lrun * alpha + rs;
            if (__any(alpha < 1.0f)) {
#pragma unroll
                for (int nt = 0; nt < 8; nt++)
                    O[nt] *= alpha;
            }
        }

        // ---- zero-shuffle PV: B-fragment = lane's OWN P-values ----
        // h(quad,b) = kt*32 + (b>=4)*16 + quad*4 + (b&3); Vt columns match via c(s).
        u32 c0[4], c1[4];
#pragma unroll
        for (int nt = 0; nt < 4; nt++) {
            c0[nt] = (u32)f2bf(S[nt][0]) | ((u32)f2bf(S[nt][1]) << 16);
            c1[nt] = (u32)f2bf(S[nt][2]) | ((u32)f2bf(S[nt][3]) << 16);
        }
#pragma unroll
        for (int kt = 0; kt < 2; kt++) {
            uint4 bq;
            bq.x = c0[2*kt];       // s = kt*32 + quad*4 + {0,1}
            bq.y = c1[2*kt];       // s = kt*32 + quad*4 + {2,3}
            bq.z = c0[2*kt+1];     // s = kt*32 + 16 + quad*4 + {0,1}
            bq.w = c1[2*kt+1];     // s = kt*32 + 16 + quad*4 + {2,3}
            bf16x8 pf = __builtin_bit_cast(bf16x8, bq);
            // ---- O^T += mfma(V^T, P^T) ----
#pragma unroll
            for (int nt = 0; nt < 8; nt++) {
                bf16x8 av = *(const bf16x8*)&Vt[(nt*16 + l15) * LV + kt*32 + quad*8];
                O[nt] = MFMA16(av, pf, O[nt]);
            }
        }
        __syncthreads();   // [B] Vt / Kl[j&1] free for next iter's staging
    }

    // ---- epilogue: O^T /= l (lane-local), pack 4 u16 per nt, store b64 ----
    {
        float inv = 1.0f / lrun;
        size_t row = rowbase + qt*64 + w*16 + l15;
        u16* outp = AO + row * HIDDIM + h * HD + quad*4;
#pragma unroll
        for (int nt = 0; nt < 8; nt++) {
            uint2 o;
            o.x = (u32)f2bf(O[nt][0] * inv) | ((u32)f2bf(O[nt][1] * inv) << 16);
            o.y = (u32)f2bf(O[nt][2] * inv) | ((u32)f2bf(O[nt][3] * inv) << 16);
            *(uint2*)(outp + nt*16) = o;
        }
    }
}

extern "C" void kernel_launch(void* const* d_in, const int* in_sizes, int n_in,
                              void* d_out, int out_size, void* d_ws, size_t ws_size,
                              hipStream_t stream) {
    (void)in_sizes; (void)n_in; (void)out_size; (void)ws_size;
    const float* x    = (const float*)d_in[0];
    const float* cosT = (const float*)d_in[1];
    const float* sinT = (const float*)d_in[2];
    const float* Wq   = (const float*)d_in[3];
    const float* Wk   = (const float*)d_in[4];
    const float* Wv   = (const float*)d_in[5];
    const float* Wo   = (const float*)d_in[6];

    char* ws = (char*)d_ws;
    u16* QKV   = (u16*)ws;                                             // 4096*3072 bf16
    u16* xb    = (u16*)(ws + (size_t)MROWS * NQKV * 2);                // 4096*2048 (then attn_out)
    u16* Wqkvt = (u16*)(ws + (size_t)MROWS * NQKV * 2 + (size_t)MROWS * HIDDIM * 2); // 3072*2048
    u16* Wot   = Wqkvt + (size_t)NQKV * KDIM;                          // 2048*2048

    prep_kernel<<<14336, 256, 0, stream>>>(x, xb, Wq, Wk, Wv, Wo, Wqkvt, Wot);
    gemm_bt<1><<<dim3(32, 24), 256, 0, stream>>>(xb, Wqkvt, QKV, NQKV);
    rotary_kernel<<<5120, 256, 0, stream>>>(QKV, cosT, sinT);
    attn_kernel<<<dim3(32, 16, 2), 256, 0, stream>>>(QKV, xb);
    gemm_bt<0><<<dim3(32, 16), 256, 0, stream>>>(xb, Wot, d_out, HIDDIM);
}

// Round 3
// 307.176 us; speedup vs baseline: 1.1624x; 1.1624x over previous
//
#include <hip/hip_runtime.h>
#include <hip/hip_bf16.h>
#include <cstdint>

typedef unsigned short u16;
typedef unsigned int u32;
typedef __bf16 bf16x8 __attribute__((ext_vector_type(8)));
typedef float f32x4 __attribute__((ext_vector_type(4)));

#define BDIM 2
#define TDIM 2048
#define HIDDIM 2048
#define NHEAD 16
#define NKVH 4
#define HD 128
#define MROWS (BDIM*TDIM)     /* 4096 */
#define NQKV 3072
#define KDIM 2048

#define MFMA16(a,b,c) __builtin_amdgcn_mfma_f32_16x16x32_bf16((a),(b),(c),0,0,0)

__device__ __forceinline__ u16 f2bf(float f) {
    __bf16 h = (__bf16)f;
    return __builtin_bit_cast(u16, h);
}
__device__ __forceinline__ float bf2f(u32 u) {
    u <<= 16;
    return __builtin_bit_cast(float, u);
}
__device__ __forceinline__ void gld16(const void* g, void* l) {
    __builtin_amdgcn_global_load_lds(
        (const __attribute__((address_space(1))) u32*)g,
        (__attribute__((address_space(3))) u32*)l, 16, 0, 0);
}

// ---------------- fused prep: x->bf16 convert + 4 weight transposes ----------------
// grid layout: [0,4096) cvt_x | [4096,8192) Wq | [8192,9216) Wk
//              [9216,10240) Wv | [10240,14336) Wo
__global__ __launch_bounds__(256) void prep_kernel(const float* __restrict__ x,
                                                   u16* __restrict__ xb,
                                                   const float* __restrict__ Wq,
                                                   const float* __restrict__ Wk,
                                                   const float* __restrict__ Wv,
                                                   const float* __restrict__ Wo,
                                                   u16* __restrict__ Wqkvt,
                                                   u16* __restrict__ Wot) {
    __shared__ float tile[32][33];
    const int bi = blockIdx.x;
    const int tid = threadIdx.x;
    if (bi < 4096) {
        size_t i = ((size_t)bi * 256 + tid) * 8;
        float4 a = *(const float4*)(x + i);
        float4 b = *(const float4*)(x + i + 4);
        uint4 v;
        v.x = (u32)f2bf(a.x) | ((u32)f2bf(a.y) << 16);
        v.y = (u32)f2bf(a.z) | ((u32)f2bf(a.w) << 16);
        v.z = (u32)f2bf(b.x) | ((u32)f2bf(b.y) << 16);
        v.w = (u32)f2bf(b.z) | ((u32)f2bf(b.w) << 16);
        *(uint4*)(xb + i) = v;
        return;
    }
    const float* src;
    u16* dst;
    int N, n0, k0;
    if (bi < 8192) {
        int t = bi - 4096; src = Wq; dst = Wqkvt; N = 2048;
        n0 = (t & 63) * 32; k0 = (t >> 6) * 32;
    } else if (bi < 9216) {
        int t = bi - 8192; src = Wk; dst = Wqkvt + (size_t)2048 * KDIM; N = 512;
        n0 = (t & 15) * 32; k0 = (t >> 4) * 32;
    } else if (bi < 10240) {
        int t = bi - 9216; src = Wv; dst = Wqkvt + (size_t)2560 * KDIM; N = 512;
        n0 = (t & 15) * 32; k0 = (t >> 4) * 32;
    } else {
        int t = bi - 10240; src = Wo; dst = Wot; N = 2048;
        n0 = (t & 63) * 32; k0 = (t >> 6) * 32;
    }
    const int tx = tid & 31, ty = tid >> 5;   // 32 x 8
#pragma unroll
    for (int r = 0; r < 4; r++)
        tile[ty + 8*r][tx] = src[(size_t)(k0 + ty + 8*r) * N + n0 + tx];
    __syncthreads();
#pragma unroll
    for (int r = 0; r < 4; r++)
        dst[(size_t)(n0 + ty + 8*r) * KDIM + k0 + tx] = f2bf(tile[tx][ty + 8*r]);
}

// ---------------- GEMM: C[m][n] = sum_k A[m][k] * Bt[n][k] ----------------
template<int OUT_BF16>
__global__ void __launch_bounds__(256, 2) gemm_bt(const u16* __restrict__ A,
                                                  const u16* __restrict__ Bt,
                                                  void* __restrict__ C, int ldc) {
    __shared__ __align__(16) u16 Al[128 * 32];
    __shared__ __align__(16) u16 Bl[128 * 32];
    const int tid = threadIdx.x;
    const int lane = tid & 63;
    const int w = tid >> 6;
    const int wm = (w & 1) * 64;
    const int wn = (w >> 1) * 64;
    const int quad = lane >> 4;
    const int l15 = lane & 15;
    const size_t bm = (size_t)blockIdx.x * 128;
    const size_t bn = (size_t)blockIdx.y * 128;

    const int srow = lane >> 2;
    const int kq = (lane & 3) ^ ((lane >> 3) & 3);
    const int i0 = 2 * w, i1 = 2 * w + 1;

    const u16* ga0 = A + (bm + i0*16 + srow) * KDIM + kq * 8;
    const u16* ga1 = A + (bm + i1*16 + srow) * KDIM + kq * 8;
    const u16* gb0 = Bt + (bn + i0*16 + srow) * KDIM + kq * 8;
    const u16* gb1 = Bt + (bn + i1*16 + srow) * KDIM + kq * 8;

    const int swz = ((quad ^ ((l15 >> 1) & 3)) << 3);
    int aoff[4], boff[4];
#pragma unroll
    for (int t = 0; t < 4; t++) {
        aoff[t] = (wm + t*16 + l15) * 32 + swz;
        boff[t] = (wn + t*16 + l15) * 32 + swz;
    }

    f32x4 acc[4][4] = {};

    for (int kt = 0; kt < KDIM / 32; kt++) {
        gld16(ga0 + kt*32, &Al[i0 * 512]);
        gld16(ga1 + kt*32, &Al[i1 * 512]);
        gld16(gb0 + kt*32, &Bl[i0 * 512]);
        gld16(gb1 + kt*32, &Bl[i1 * 512]);
        __syncthreads();
        bf16x8 af[4], bfv[4];
#pragma unroll
        for (int t = 0; t < 4; t++) {
            af[t]  = *(const bf16x8*)&Al[aoff[t]];
            bfv[t] = *(const bf16x8*)&Bl[boff[t]];
        }
#pragma unroll
        for (int mt = 0; mt < 4; mt++)
#pragma unroll
            for (int nt = 0; nt < 4; nt++)
                acc[mt][nt] = MFMA16(af[mt], bfv[nt], acc[mt][nt]);
        __syncthreads();
    }

#pragma unroll
    for (int mt = 0; mt < 4; mt++) {
        size_t m0 = bm + wm + mt*16 + quad*4;
#pragma unroll
        for (int nt = 0; nt < 4; nt++) {
            size_t n = bn + wn + nt*16 + l15;
#pragma unroll
            for (int r = 0; r < 4; r++) {
                if (OUT_BF16)
                    ((u16*)C)[(m0 + r) * (size_t)ldc + n] = f2bf(acc[mt][nt][r]);
                else
                    ((float*)C)[(m0 + r) * (size_t)ldc + n] = acc[mt][nt][r];
            }
        }
    }
}

// ---------------- rotary (in-place on Q and K parts of QKV), Q gets scale folded ----------------
__global__ __launch_bounds__(256) void rotary_kernel(u16* __restrict__ QKV,
                                                     const float* __restrict__ cosT,
                                                     const float* __restrict__ sinT) {
    int i = blockIdx.x * 256 + threadIdx.x;   // < 4096*320
    int m = i / 320;
    int rem = i - m * 320;
    int head = rem >> 4;
    int d0 = (rem & 15) << 2;                 // 0..60
    int t = m & (TDIM - 1);
    int col;
    float sc;
    if (head < NHEAD) {
        col = head * HD + d0;
        sc = 0.08838834764831845f * 1.4426950408889634f; // 1/sqrt(128) * log2(e)
    } else {
        col = HIDDIM + (head - NHEAD) * HD + d0;
        sc = 1.0f;
    }
    u16* p0 = QKV + (size_t)m * NQKV + col;
    u16* p1 = p0 + 64;
    float4 cv = *(const float4*)(cosT + t * HD + d0);
    float4 sv = *(const float4*)(sinT + t * HD + d0);
    uint2 qa = *(const uint2*)p0;
    uint2 qb = *(const uint2*)p1;
    float f0[4] = { bf2f(qa.x & 0xffffu), bf2f(qa.x >> 16), bf2f(qa.y & 0xffffu), bf2f(qa.y >> 16) };
    float f1[4] = { bf2f(qb.x & 0xffffu), bf2f(qb.x >> 16), bf2f(qb.y & 0xffffu), bf2f(qb.y >> 16) };
    float c[4] = { cv.x, cv.y, cv.z, cv.w };
    float s[4] = { sv.x, sv.y, sv.z, sv.w };
    u16 o0[4], o1[4];
#pragma unroll
    for (int k = 0; k < 4; k++) {
        o0[k] = f2bf((f0[k] * c[k] - f1[k] * s[k]) * sc);
        o1[k] = f2bf((f1[k] * c[k] + f0[k] * s[k]) * sc);
    }
    uint2 w0, w1;
    w0.x = (u32)o0[0] | ((u32)o0[1] << 16);
    w0.y = (u32)o0[2] | ((u32)o0[3] << 16);
    w1.x = (u32)o1[0] | ((u32)o1[1] << 16);
    w1.y = (u32)o1[2] | ((u32)o1[3] << 16);
    *(uint2*)p0 = w0;
    *(uint2*)p1 = w1;
}

// ---------------- flash attention, causal, GQA ----------------
// Swapped-operand core: S^T = mfma(K,Q) so each lane owns ONE q-row (q=w*16+l15,
// stats replicated over quads). Softmax stats lane-local after two __shfl_xor.
// Zero-shuffle PV: B-fragment = lane's OWN 8 P-values under the k-mapping
// h(quad,b) = kt*32 + (b>=4)*16 + quad*4 + (b&3); Vt stored at bit-permuted
// columns c(s) (bit4 <-> bits3:2) so one b128 read matches the same mapping.
// O^T = mfma(V^T, P^T): alpha / 1/l rescales lane-local. No P LDS buffer.
// Schedule: balanced pairs (pa, 31-pa) -> 33 iters/block, 512 blocks = 2/CU,
// all co-resident, uniform finish (round-2's 1024 unbalanced blocks dropped
// avg occupancy to 13.7% and cost +40%; this restores it).
// T13 defer-max: skip O-rescale unless running max grows >8 (log2 domain).
// T5 setprio around MFMA clusters.
__global__ void __launch_bounds__(256, 2) attn_kernel(const u16* __restrict__ QKV,
                                                      u16* __restrict__ AO) {
    constexpr int LV = 72;   // Vt row stride
    __shared__ __align__(16) u16 Kl[2][64 * 128];  // double-buffered K tile
    __shared__ __align__(16) u16 Vt[128 * LV];     // V transposed [d][c(s)]

    const int pa = blockIdx.x;   // pair index 0..15
    const int h  = blockIdx.y;
    const int b  = blockIdx.z;
    const int kh = h >> 2;
    const int tid = threadIdx.x;
    const int lane = tid & 63;
    const int w = tid >> 6;
    const int quad = lane >> 4;
    const int l15 = lane & 15;

    const size_t rowbase = (size_t)b * TDIM;
    const u16* Qb = QKV + rowbase * NQKV + h * HD;
    const u16* Kb = QKV + rowbase * NQKV + HIDDIM + kh * HD;
    const u16* Vb = Kb + NKVH * HD;

    // K staging: instr i stages rows w*16+i*4..+3; chunk swizzle c ^= (row&7)
    int krow[4], kgch[4];
#pragma unroll
    for (int i = 0; i < 4; i++) {
        krow[i] = w*16 + i*4 + quad;
        kgch[i] = l15 ^ (krow[i] & 7);
    }
    // V staging lane mapping: sp (s-pair), dch (d-chunk of 8)
    const int sp0 = tid & 31, dch0 = tid >> 5, dch1 = dch0 + 8;
    // bit-permuted Vt column: swap s-bit4 with s-bits3:2  (c(s+1)=c(s)+1, s even)
    const int s0v = sp0 * 2;
    const int ccv = (s0v & ~0x1C) | ((s0v & 0x0C) << 1) | ((s0v & 0x10) >> 2);

#pragma unroll 1
    for (int ph = 0; ph < 2; ph++) {
        const int qt = ph ? (31 - pa) : pa;   // Q-tile index, 64 rows

        // Q fragments: wave w owns rows qt*64 + w*16 .. +15 (pre-scaled 1/sqrt(d)*log2e)
        bf16x8 qf[4];
        {
            const u16* qr = Qb + (size_t)(qt*64 + w*16 + l15) * NQKV;
#pragma unroll
            for (int kt = 0; kt < 4; kt++)
                qf[kt] = *(const bf16x8*)(qr + kt*32 + quad*8);
        }
        f32x4 O[8] = {};      // O^T: O[nt][r] = O^T[d=nt*16+quad*4+r][q=w*16+l15]
        float mrun = -1e30f, lrun = 0.0f;

        // ---- prologue: prefetch K(0) -> Kl[0], V(0) -> regs ----
#pragma unroll
        for (int i = 0; i < 4; i++)
            gld16(Kb + (size_t)krow[i] * NQKV + kgch[i]*8, &Kl[0][(w*16 + i*4) * 128]);
        uint4 vr0a, vr0b, vr1a, vr1b;
        {
            const u16* g0 = Vb + (size_t)s0v * NQKV + dch0*8;
            vr0a = *(const uint4*)g0;
            vr0b = *(const uint4*)(g0 + NQKV);
            const u16* g1 = Vb + (size_t)s0v * NQKV + dch1*8;
            vr1a = *(const uint4*)g1;
            vr1b = *(const uint4*)(g1 + NQKV);
        }

#pragma unroll 1
        for (int j = 0; j <= qt; j++) {
            // ---- write V(j) regs -> Vt at permuted columns (2 lanes/bank, free) ----
            {
                u32 ra[4] = { vr0a.x, vr0a.y, vr0a.z, vr0a.w };
                u32 rb[4] = { vr0b.x, vr0b.y, vr0b.z, vr0b.w };
                int d0 = dch0*8;
#pragma unroll
                for (int k2 = 0; k2 < 4; k2++) {
                    u32 lo = (ra[k2] & 0xffffu) | (rb[k2] << 16);
                    u32 hi = (ra[k2] >> 16) | (rb[k2] & 0xffff0000u);
                    *(u32*)&Vt[(d0 + 2*k2)     * LV + ccv] = lo;
                    *(u32*)&Vt[(d0 + 2*k2 + 1) * LV + ccv] = hi;
                }
                u32 rc[4] = { vr1a.x, vr1a.y, vr1a.z, vr1a.w };
                u32 rd[4] = { vr1b.x, vr1b.y, vr1b.z, vr1b.w };
                d0 = dch1*8;
#pragma unroll
                for (int k2 = 0; k2 < 4; k2++) {
                    u32 lo = (rc[k2] & 0xffffu) | (rd[k2] << 16);
                    u32 hi = (rc[k2] >> 16) | (rd[k2] & 0xffff0000u);
                    *(u32*)&Vt[(d0 + 2*k2)     * LV + ccv] = lo;
                    *(u32*)&Vt[(d0 + 2*k2 + 1) * LV + ccv] = hi;
                }
            }
            __syncthreads();   // [A] K(j) landed (vmcnt drain), Vt visible

            // ---- prefetch K(j+1), V(j+1) (hidden behind this iter's compute) ----
            if (j < qt) {
                const u16* Kbn = Kb + (size_t)(j+1) * 64 * NQKV;
                u16* kl = Kl[(j+1) & 1];
#pragma unroll
                for (int i = 0; i < 4; i++)
                    gld16(Kbn + (size_t)krow[i] * NQKV + kgch[i]*8, &kl[(w*16 + i*4) * 128]);
                const u16* Vbn = Vb + (size_t)(j+1) * 64 * NQKV;
                const u16* g0 = Vbn + (size_t)s0v * NQKV + dch0*8;
                vr0a = *(const uint4*)g0;
                vr0b = *(const uint4*)(g0 + NQKV);
                const u16* g1 = Vbn + (size_t)s0v * NQKV + dch1*8;
                vr1a = *(const uint4*)g1;
                vr1b = *(const uint4*)(g1 + NQKV);
            }

            // ---- S^T = mfma(K, Q): S[nt][r] = scores[q=w*16+l15][s=nt*16+quad*4+r] ----
            const u16* kl = Kl[j & 1];
            f32x4 S[4] = {};
            __builtin_amdgcn_s_setprio(1);
#pragma unroll
            for (int kt = 0; kt < 4; kt++) {
                int p = (kt*4 + quad) ^ (l15 & 7);
#pragma unroll
                for (int nt = 0; nt < 4; nt++) {
                    bf16x8 afr = *(const bf16x8*)&kl[(nt*16 + l15)*128 + p*8];
                    S[nt] = MFMA16(afr, qf[kt], S[nt]);
                }
            }
            __builtin_amdgcn_s_setprio(0);

            // ---- causal mask: only the diagonal tile is boundary ----
            if (j == qt) {
                const int qloc = w*16 + l15;
#pragma unroll
                for (int nt = 0; nt < 4; nt++) {
                    const int sb = nt*16 + quad*4;
#pragma unroll
                    for (int r = 0; r < 4; r++)
                        if (sb + r > qloc) S[nt][r] = -1e30f;
                }
            }

            // ---- online softmax, lane-local row; T13 defer-max (THR=8, log2 dom) ----
            bool grow;
            {
                float mx0 = fmaxf(fmaxf(S[0][0], S[0][1]), fmaxf(S[0][2], S[0][3]));
                float mx1 = fmaxf(fmaxf(S[1][0], S[1][1]), fmaxf(S[1][2], S[1][3]));
                float mx2 = fmaxf(fmaxf(S[2][0], S[2][1]), fmaxf(S[2][2], S[2][3]));
                float mx3 = fmaxf(fmaxf(S[3][0], S[3][1]), fmaxf(S[3][2], S[3][3]));
                float mx = fmaxf(fmaxf(mx0, mx1), fmaxf(mx2, mx3));
                mx = fmaxf(mx, __shfl_xor(mx, 16, 64));   // across quad pairs
                mx = fmaxf(mx, __shfl_xor(mx, 32, 64));   // across halves
                grow = __any(mx > mrun + 8.0f);
                float alpha = 1.0f;
                if (grow) {
                    float mnew = fmaxf(mrun, mx);
                    alpha = __builtin_amdgcn_exp2f(mrun - mnew);
                    mrun = mnew;
                }
                float rs = 0.0f;
#pragma unroll
                for (int nt = 0; nt < 4; nt++)
#pragma unroll
                    for (int r = 0; r < 4; r++) {
                        float pv = __builtin_amdgcn_exp2f(S[nt][r] - mrun);
                        S[nt][r] = pv;
                        rs += pv;
                    }
                rs += __shfl_xor(rs, 16, 64);
                rs += __shfl_xor(rs, 32, 64);
                lrun = lrun * alpha + rs;
                if (grow) {
#pragma unroll
                    for (int nt = 0; nt < 8; nt++)
                        O[nt] *= alpha;
                }
            }

            // ---- zero-shuffle PV: B-fragment = lane's OWN P-values ----
            u32 c0[4], c1[4];
#pragma unroll
            for (int nt = 0; nt < 4; nt++) {
                c0[nt] = (u32)f2bf(S[nt][0]) | ((u32)f2bf(S[nt][1]) << 16);
                c1[nt] = (u32)f2bf(S[nt][2]) | ((u32)f2bf(S[nt][3]) << 16);
            }
            __builtin_amdgcn_s_setprio(1);
#pragma unroll
            for (int kt = 0; kt < 2; kt++) {
                uint4 bq;
                bq.x = c0[2*kt];       // s = kt*32 + quad*4 + {0,1}
                bq.y = c1[2*kt];       // s = kt*32 + quad*4 + {2,3}
                bq.z = c0[2*kt+1];     // s = kt*32 + 16 + quad*4 + {0,1}
                bq.w = c1[2*kt+1];     // s = kt*32 + 16 + quad*4 + {2,3}
                bf16x8 pf = __builtin_bit_cast(bf16x8, bq);
                // ---- O^T += mfma(V^T, P^T) ----
#pragma unroll
                for (int nt = 0; nt < 8; nt++) {
                    bf16x8 av = *(const bf16x8*)&Vt[(nt*16 + l15) * LV + kt*32 + quad*8];
                    O[nt] = MFMA16(av, pf, O[nt]);
                }
            }
            __builtin_amdgcn_s_setprio(0);
            __syncthreads();   // [B] Vt / Kl[j&1] free for next iter's staging
        }

        // ---- epilogue: O^T /= l (lane-local), pack, store b64 ----
        {
            float inv = 1.0f / lrun;
            size_t row = rowbase + qt*64 + w*16 + l15;
            u16* outp = AO + row * HIDDIM + h * HD + quad*4;
#pragma unroll
            for (int nt = 0; nt < 8; nt++) {
                uint2 o;
                o.x = (u32)f2bf(O[nt][0] * inv) | ((u32)f2bf(O[nt][1] * inv) << 16);
                o.y = (u32)f2bf(O[nt][2] * inv) | ((u32)f2bf(O[nt][3] * inv) << 16);
                *(uint2*)(outp + nt*16) = o;
            }
        }
    }
}

extern "C" void kernel_launch(void* const* d_in, const int* in_sizes, int n_in,
                              void* d_out, int out_size, void* d_ws, size_t ws_size,
                              hipStream_t stream) {
    (void)in_sizes; (void)n_in; (void)out_size; (void)ws_size;
    const float* x    = (const float*)d_in[0];
    const float* cosT = (const float*)d_in[1];
    const float* sinT = (const float*)d_in[2];
    const float* Wq   = (const float*)d_in[3];
    const float* Wk   = (const float*)d_in[4];
    const float* Wv   = (const float*)d_in[5];
    const float* Wo   = (const float*)d_in[6];

    char* ws = (char*)d_ws;
    u16* QKV   = (u16*)ws;                                             // 4096*3072 bf16
    u16* xb    = (u16*)(ws + (size_t)MROWS * NQKV * 2);                // 4096*2048 (then attn_out)
    u16* Wqkvt = (u16*)(ws + (size_t)MROWS * NQKV * 2 + (size_t)MROWS * HIDDIM * 2); // 3072*2048
    u16* Wot   = Wqkvt + (size_t)NQKV * KDIM;                          // 2048*2048

    prep_kernel<<<14336, 256, 0, stream>>>(x, xb, Wq, Wk, Wv, Wo, Wqkvt, Wot);
    gemm_bt<1><<<dim3(32, 24), 256, 0, stream>>>(xb, Wqkvt, QKV, NQKV);
    rotary_kernel<<<5120, 256, 0, stream>>>(QKV, cosT, sinT);
    attn_kernel<<<dim3(16, 16, 2), 256, 0, stream>>>(QKV, xb);
    gemm_bt<0><<<dim3(32, 16), 256, 0, stream>>>(xb, Wot, d_out, HIDDIM);
}

// Round 4
// 303.415 us; speedup vs baseline: 1.1768x; 1.0124x over previous
//
#include <hip/hip_runtime.h>
#include <hip/hip_bf16.h>
#include <cstdint>

typedef unsigned short u16;
typedef unsigned int u32;
typedef __bf16 bf16x8 __attribute__((ext_vector_type(8)));
typedef float f32x4 __attribute__((ext_vector_type(4)));

#define BDIM 2
#define TDIM 2048
#define HIDDIM 2048
#define NHEAD 16
#define NKVH 4
#define HD 128
#define MROWS (BDIM*TDIM)     /* 4096 */
#define NQKV 3072
#define KDIM 2048

#define MFMA16(a,b,c) __builtin_amdgcn_mfma_f32_16x16x32_bf16((a),(b),(c),0,0,0)

__device__ __forceinline__ u16 f2bf(float f) {
    __bf16 h = (__bf16)f;
    return __builtin_bit_cast(u16, h);
}
__device__ __forceinline__ float bf2f(u32 u) {
    u <<= 16;
    return __builtin_bit_cast(float, u);
}
__device__ __forceinline__ void gld16(const void* g, void* l) {
    __builtin_amdgcn_global_load_lds(
        (const __attribute__((address_space(1))) u32*)g,
        (__attribute__((address_space(3))) u32*)l, 16, 0, 0);
}

// ---------------- fused prep: x->bf16 convert + 4 weight transposes ----------------
// grid layout: [0,4096) cvt_x | [4096,8192) Wq | [8192,9216) Wk
//              [9216,10240) Wv | [10240,14336) Wo
__global__ __launch_bounds__(256) void prep_kernel(const float* __restrict__ x,
                                                   u16* __restrict__ xb,
                                                   const float* __restrict__ Wq,
                                                   const float* __restrict__ Wk,
                                                   const float* __restrict__ Wv,
                                                   const float* __restrict__ Wo,
                                                   u16* __restrict__ Wqkvt,
                                                   u16* __restrict__ Wot) {
    __shared__ float tile[32][33];
    const int bi = blockIdx.x;
    const int tid = threadIdx.x;
    if (bi < 4096) {
        size_t i = ((size_t)bi * 256 + tid) * 8;
        float4 a = *(const float4*)(x + i);
        float4 b = *(const float4*)(x + i + 4);
        uint4 v;
        v.x = (u32)f2bf(a.x) | ((u32)f2bf(a.y) << 16);
        v.y = (u32)f2bf(a.z) | ((u32)f2bf(a.w) << 16);
        v.z = (u32)f2bf(b.x) | ((u32)f2bf(b.y) << 16);
        v.w = (u32)f2bf(b.z) | ((u32)f2bf(b.w) << 16);
        *(uint4*)(xb + i) = v;
        return;
    }
    const float* src;
    u16* dst;
    int N, n0, k0;
    if (bi < 8192) {
        int t = bi - 4096; src = Wq; dst = Wqkvt; N = 2048;
        n0 = (t & 63) * 32; k0 = (t >> 6) * 32;
    } else if (bi < 9216) {
        int t = bi - 8192; src = Wk; dst = Wqkvt + (size_t)2048 * KDIM; N = 512;
        n0 = (t & 15) * 32; k0 = (t >> 4) * 32;
    } else if (bi < 10240) {
        int t = bi - 9216; src = Wv; dst = Wqkvt + (size_t)2560 * KDIM; N = 512;
        n0 = (t & 15) * 32; k0 = (t >> 4) * 32;
    } else {
        int t = bi - 10240; src = Wo; dst = Wot; N = 2048;
        n0 = (t & 63) * 32; k0 = (t >> 6) * 32;
    }
    const int tx = tid & 31, ty = tid >> 5;   // 32 x 8
#pragma unroll
    for (int r = 0; r < 4; r++)
        tile[ty + 8*r][tx] = src[(size_t)(k0 + ty + 8*r) * N + n0 + tx];
    __syncthreads();
#pragma unroll
    for (int r = 0; r < 4; r++)
        dst[(size_t)(n0 + ty + 8*r) * KDIM + k0 + tx] = f2bf(tile[tx][ty + 8*r]);
}

// ---------------- GEMM: C[m][n] = sum_k A[m][k] * Bt[n][k] ----------------
template<int OUT_BF16>
__global__ void __launch_bounds__(256, 2) gemm_bt(const u16* __restrict__ A,
                                                  const u16* __restrict__ Bt,
                                                  void* __restrict__ C, int ldc) {
    __shared__ __align__(16) u16 Al[128 * 32];
    __shared__ __align__(16) u16 Bl[128 * 32];
    const int tid = threadIdx.x;
    const int lane = tid & 63;
    const int w = tid >> 6;
    const int wm = (w & 1) * 64;
    const int wn = (w >> 1) * 64;
    const int quad = lane >> 4;
    const int l15 = lane & 15;
    const size_t bm = (size_t)blockIdx.x * 128;
    const size_t bn = (size_t)blockIdx.y * 128;

    const int srow = lane >> 2;
    const int kq = (lane & 3) ^ ((lane >> 3) & 3);
    const int i0 = 2 * w, i1 = 2 * w + 1;

    const u16* ga0 = A + (bm + i0*16 + srow) * KDIM + kq * 8;
    const u16* ga1 = A + (bm + i1*16 + srow) * KDIM + kq * 8;
    const u16* gb0 = Bt + (bn + i0*16 + srow) * KDIM + kq * 8;
    const u16* gb1 = Bt + (bn + i1*16 + srow) * KDIM + kq * 8;

    const int swz = ((quad ^ ((l15 >> 1) & 3)) << 3);
    int aoff[4], boff[4];
#pragma unroll
    for (int t = 0; t < 4; t++) {
        aoff[t] = (wm + t*16 + l15) * 32 + swz;
        boff[t] = (wn + t*16 + l15) * 32 + swz;
    }

    f32x4 acc[4][4] = {};

    for (int kt = 0; kt < KDIM / 32; kt++) {
        gld16(ga0 + kt*32, &Al[i0 * 512]);
        gld16(ga1 + kt*32, &Al[i1 * 512]);
        gld16(gb0 + kt*32, &Bl[i0 * 512]);
        gld16(gb1 + kt*32, &Bl[i1 * 512]);
        __syncthreads();
        bf16x8 af[4], bfv[4];
#pragma unroll
        for (int t = 0; t < 4; t++) {
            af[t]  = *(const bf16x8*)&Al[aoff[t]];
            bfv[t] = *(const bf16x8*)&Bl[boff[t]];
        }
#pragma unroll
        for (int mt = 0; mt < 4; mt++)
#pragma unroll
            for (int nt = 0; nt < 4; nt++)
                acc[mt][nt] = MFMA16(af[mt], bfv[nt], acc[mt][nt]);
        __syncthreads();
    }

#pragma unroll
    for (int mt = 0; mt < 4; mt++) {
        size_t m0 = bm + wm + mt*16 + quad*4;
#pragma unroll
        for (int nt = 0; nt < 4; nt++) {
            size_t n = bn + wn + nt*16 + l15;
#pragma unroll
            for (int r = 0; r < 4; r++) {
                if (OUT_BF16)
                    ((u16*)C)[(m0 + r) * (size_t)ldc + n] = f2bf(acc[mt][nt][r]);
                else
                    ((float*)C)[(m0 + r) * (size_t)ldc + n] = acc[mt][nt][r];
            }
        }
    }
}

// ---------------- rotary (in-place on Q and K parts of QKV), Q gets scale folded ----------------
__global__ __launch_bounds__(256) void rotary_kernel(u16* __restrict__ QKV,
                                                     const float* __restrict__ cosT,
                                                     const float* __restrict__ sinT) {
    int i = blockIdx.x * 256 + threadIdx.x;   // < 4096*320
    int m = i / 320;
    int rem = i - m * 320;
    int head = rem >> 4;
    int d0 = (rem & 15) << 2;                 // 0..60
    int t = m & (TDIM - 1);
    int col;
    float sc;
    if (head < NHEAD) {
        col = head * HD + d0;
        sc = 0.08838834764831845f * 1.4426950408889634f; // 1/sqrt(128) * log2(e)
    } else {
        col = HIDDIM + (head - NHEAD) * HD + d0;
        sc = 1.0f;
    }
    u16* p0 = QKV + (size_t)m * NQKV + col;
    u16* p1 = p0 + 64;
    float4 cv = *(const float4*)(cosT + t * HD + d0);
    float4 sv = *(const float4*)(sinT + t * HD + d0);
    uint2 qa = *(const uint2*)p0;
    uint2 qb = *(const uint2*)p1;
    float f0[4] = { bf2f(qa.x & 0xffffu), bf2f(qa.x >> 16), bf2f(qa.y & 0xffffu), bf2f(qa.y >> 16) };
    float f1[4] = { bf2f(qb.x & 0xffffu), bf2f(qb.x >> 16), bf2f(qb.y & 0xffffu), bf2f(qb.y >> 16) };
    float c[4] = { cv.x, cv.y, cv.z, cv.w };
    float s[4] = { sv.x, sv.y, sv.z, sv.w };
    u16 o0[4], o1[4];
#pragma unroll
    for (int k = 0; k < 4; k++) {
        o0[k] = f2bf((f0[k] * c[k] - f1[k] * s[k]) * sc);
        o1[k] = f2bf((f1[k] * c[k] + f0[k] * s[k]) * sc);
    }
    uint2 w0, w1;
    w0.x = (u32)o0[0] | ((u32)o0[1] << 16);
    w0.y = (u32)o0[2] | ((u32)o0[3] << 16);
    w1.x = (u32)o1[0] | ((u32)o1[1] << 16);
    w1.y = (u32)o1[2] | ((u32)o1[3] << 16);
    *(uint2*)p0 = w0;
    *(uint2*)p1 = w1;
}

// ---------------- flash attention, causal, GQA ----------------
// Swapped-operand core: S^T = mfma(K,Q) so each lane owns ONE q-row (q=w*16+l15,
// stats replicated over quads). Softmax stats lane-local after two __shfl_xor.
// Zero-shuffle PV: B-fragment = lane's OWN 8 P-values under the k-mapping
// h(quad,b) = kt*32 + (b>=4)*16 + quad*4 + (b&3); Vt stored at bit-permuted
// columns c(s) (bit4 <-> bits3:2) so one b128 read matches the same mapping.
// O^T = mfma(V^T, P^T): alpha / 1/l rescales lane-local. No P LDS buffer.
// SINGLE barrier per KV-iter: K *and* Vt are double-buffered, so iter j+1's
// staging never touches buffers read in iter j -> barrier [B] deleted. The
// vmcnt drain for K(j+1)/V(j+1) now happens a FULL iter after issue (was:
// softmax+PV window only). LDS = 32K (K dbuf) + 36K (Vt dbuf) = 69.6 KB ->
// still 2 blocks/CU. Balanced pairs (pa, 31-pa): 33 iters/block, 512 blocks,
// all co-resident, uniform finish. T13 defer-max, T5 setprio retained.
__global__ void __launch_bounds__(256, 2) attn_kernel(const u16* __restrict__ QKV,
                                                      u16* __restrict__ AO) {
    constexpr int LV = 72;   // Vt row stride
    __shared__ __align__(16) u16 Kl[2][64 * 128];   // double-buffered K tile
    __shared__ __align__(16) u16 Vt[2][128 * LV];   // double-buffered V^T [d][c(s)]

    const int pa = blockIdx.x;   // pair index 0..15
    const int h  = blockIdx.y;
    const int b  = blockIdx.z;
    const int kh = h >> 2;
    const int tid = threadIdx.x;
    const int lane = tid & 63;
    const int w = tid >> 6;
    const int quad = lane >> 4;
    const int l15 = lane & 15;

    const size_t rowbase = (size_t)b * TDIM;
    const u16* Qb = QKV + rowbase * NQKV + h * HD;
    const u16* Kb = QKV + rowbase * NQKV + HIDDIM + kh * HD;
    const u16* Vb = Kb + NKVH * HD;

    // K staging: instr i stages rows w*16+i*4..+3; chunk swizzle c ^= (row&7)
    int krow[4], kgch[4];
#pragma unroll
    for (int i = 0; i < 4; i++) {
        krow[i] = w*16 + i*4 + quad;
        kgch[i] = l15 ^ (krow[i] & 7);
    }
    // V staging lane mapping: sp (s-pair), dch (d-chunk of 8)
    const int sp0 = tid & 31, dch0 = tid >> 5, dch1 = dch0 + 8;
    // bit-permuted Vt column: swap s-bit4 with s-bits3:2  (c(s+1)=c(s)+1, s even)
    const int s0v = sp0 * 2;
    const int ccv = (s0v & ~0x1C) | ((s0v & 0x0C) << 1) | ((s0v & 0x10) >> 2);

#pragma unroll 1
    for (int ph = 0; ph < 2; ph++) {
        const int qt = ph ? (31 - pa) : pa;   // Q-tile index, 64 rows

        // Q fragments: wave w owns rows qt*64 + w*16 .. +15 (pre-scaled 1/sqrt(d)*log2e)
        bf16x8 qf[4];
        {
            const u16* qr = Qb + (size_t)(qt*64 + w*16 + l15) * NQKV;
#pragma unroll
            for (int kt = 0; kt < 4; kt++)
                qf[kt] = *(const bf16x8*)(qr + kt*32 + quad*8);
        }
        f32x4 O[8] = {};      // O^T: O[nt][r] = O^T[d=nt*16+quad*4+r][q=w*16+l15]
        float mrun = -1e30f, lrun = 0.0f;

        __syncthreads();   // prev phase's LDS reads done before re-staging

        // ---- prologue: V(0) -> regs, Vt[0] write, K(0) gld16 -> Kl[0] ----
        uint4 vr0a, vr0b, vr1a, vr1b;
        {
            const u16* g0 = Vb + (size_t)s0v * NQKV + dch0*8;
            vr0a = *(const uint4*)g0;
            vr0b = *(const uint4*)(g0 + NQKV);
            const u16* g1 = Vb + (size_t)s0v * NQKV + dch1*8;
            vr1a = *(const uint4*)g1;
            vr1b = *(const uint4*)(g1 + NQKV);
        }
#pragma unroll
        for (int i = 0; i < 4; i++)
            gld16(Kb + (size_t)krow[i] * NQKV + kgch[i]*8, &Kl[0][(w*16 + i*4) * 128]);
        {
            u16* vt = &Vt[0][0];
            u32 ra[4] = { vr0a.x, vr0a.y, vr0a.z, vr0a.w };
            u32 rb[4] = { vr0b.x, vr0b.y, vr0b.z, vr0b.w };
            int d0 = dch0*8;
#pragma unroll
            for (int k2 = 0; k2 < 4; k2++) {
                u32 lo = (ra[k2] & 0xffffu) | (rb[k2] << 16);
                u32 hi = (ra[k2] >> 16) | (rb[k2] & 0xffff0000u);
                *(u32*)&vt[(d0 + 2*k2)     * LV + ccv] = lo;
                *(u32*)&vt[(d0 + 2*k2 + 1) * LV + ccv] = hi;
            }
            u32 rc[4] = { vr1a.x, vr1a.y, vr1a.z, vr1a.w };
            u32 rd[4] = { vr1b.x, vr1b.y, vr1b.z, vr1b.w };
            d0 = dch1*8;
#pragma unroll
            for (int k2 = 0; k2 < 4; k2++) {
                u32 lo = (rc[k2] & 0xffffu) | (rd[k2] << 16);
                u32 hi = (rc[k2] >> 16) | (rd[k2] & 0xffff0000u);
                *(u32*)&vt[(d0 + 2*k2)     * LV + ccv] = lo;
                *(u32*)&vt[(d0 + 2*k2 + 1) * LV + ccv] = hi;
            }
        }

#pragma unroll 1
        for (int j = 0; j <= qt; j++) {
            __syncthreads();   // K(j) in Kl[j&1] landed; Vt[j&1] visible

            // ---- prefetch V(j+1) -> regs, K(j+1) gld16 (hidden under full iter) ----
            if (j < qt) {
                const u16* Vbn = Vb + (size_t)(j+1) * 64 * NQKV;
                const u16* g0 = Vbn + (size_t)s0v * NQKV + dch0*8;
                vr0a = *(const uint4*)g0;
                vr0b = *(const uint4*)(g0 + NQKV);
                const u16* g1 = Vbn + (size_t)s0v * NQKV + dch1*8;
                vr1a = *(const uint4*)g1;
                vr1b = *(const uint4*)(g1 + NQKV);
                const u16* Kbn = Kb + (size_t)(j+1) * 64 * NQKV;
                u16* kl = &Kl[(j+1) & 1][0];
#pragma unroll
                for (int i = 0; i < 4; i++)
                    gld16(Kbn + (size_t)krow[i] * NQKV + kgch[i]*8, &kl[(w*16 + i*4) * 128]);
            }

            // ---- S^T = mfma(K, Q): S[nt][r] = scores[q=w*16+l15][s=nt*16+quad*4+r] ----
            const u16* kl = &Kl[j & 1][0];
            f32x4 S[4] = {};
            __builtin_amdgcn_s_setprio(1);
#pragma unroll
            for (int kt = 0; kt < 4; kt++) {
                int p = (kt*4 + quad) ^ (l15 & 7);
#pragma unroll
                for (int nt = 0; nt < 4; nt++) {
                    bf16x8 afr = *(const bf16x8*)&kl[(nt*16 + l15)*128 + p*8];
                    S[nt] = MFMA16(afr, qf[kt], S[nt]);
                }
            }
            __builtin_amdgcn_s_setprio(0);

            // ---- causal mask: only the diagonal tile is boundary ----
            if (j == qt) {
                const int qloc = w*16 + l15;
#pragma unroll
                for (int nt = 0; nt < 4; nt++) {
                    const int sb = nt*16 + quad*4;
#pragma unroll
                    for (int r = 0; r < 4; r++)
                        if (sb + r > qloc) S[nt][r] = -1e30f;
                }
            }

            // ---- online softmax, lane-local row; T13 defer-max (THR=8, log2 dom) ----
            bool grow;
            {
                float mx0 = fmaxf(fmaxf(S[0][0], S[0][1]), fmaxf(S[0][2], S[0][3]));
                float mx1 = fmaxf(fmaxf(S[1][0], S[1][1]), fmaxf(S[1][2], S[1][3]));
                float mx2 = fmaxf(fmaxf(S[2][0], S[2][1]), fmaxf(S[2][2], S[2][3]));
                float mx3 = fmaxf(fmaxf(S[3][0], S[3][1]), fmaxf(S[3][2], S[3][3]));
                float mx = fmaxf(fmaxf(mx0, mx1), fmaxf(mx2, mx3));
                mx = fmaxf(mx, __shfl_xor(mx, 16, 64));   // across quad pairs
                mx = fmaxf(mx, __shfl_xor(mx, 32, 64));   // across halves
                grow = __any(mx > mrun + 8.0f);
                float alpha = 1.0f;
                if (grow) {
                    float mnew = fmaxf(mrun, mx);
                    alpha = __builtin_amdgcn_exp2f(mrun - mnew);
                    mrun = mnew;
                }
                float rs = 0.0f;
#pragma unroll
                for (int nt = 0; nt < 4; nt++)
#pragma unroll
                    for (int r = 0; r < 4; r++) {
                        float pv = __builtin_amdgcn_exp2f(S[nt][r] - mrun);
                        S[nt][r] = pv;
                        rs += pv;
                    }
                rs += __shfl_xor(rs, 16, 64);
                rs += __shfl_xor(rs, 32, 64);
                lrun = lrun * alpha + rs;
                if (grow) {
#pragma unroll
                    for (int nt = 0; nt < 8; nt++)
                        O[nt] *= alpha;
                }
            }

            // ---- zero-shuffle PV: B-fragment = lane's OWN P-values ----
            u32 c0[4], c1[4];
#pragma unroll
            for (int nt = 0; nt < 4; nt++) {
                c0[nt] = (u32)f2bf(S[nt][0]) | ((u32)f2bf(S[nt][1]) << 16);
                c1[nt] = (u32)f2bf(S[nt][2]) | ((u32)f2bf(S[nt][3]) << 16);
            }
            const u16* vt = &Vt[j & 1][0];
            __builtin_amdgcn_s_setprio(1);
#pragma unroll
            for (int kt = 0; kt < 2; kt++) {
                uint4 bq;
                bq.x = c0[2*kt];       // s = kt*32 + quad*4 + {0,1}
                bq.y = c1[2*kt];       // s = kt*32 + quad*4 + {2,3}
                bq.z = c0[2*kt+1];     // s = kt*32 + 16 + quad*4 + {0,1}
                bq.w = c1[2*kt+1];     // s = kt*32 + 16 + quad*4 + {2,3}
                bf16x8 pf = __builtin_bit_cast(bf16x8, bq);
                // ---- O^T += mfma(V^T, P^T) ----
#pragma unroll
                for (int nt = 0; nt < 8; nt++) {
                    bf16x8 av = *(const bf16x8*)&vt[(nt*16 + l15) * LV + kt*32 + quad*8];
                    O[nt] = MFMA16(av, pf, O[nt]);
                }
            }
            __builtin_amdgcn_s_setprio(0);

            // ---- write V(j+1) regs -> Vt[(j+1)&1] (other buffer: no barrier) ----
            if (j < qt) {
                u16* vtn = &Vt[(j+1) & 1][0];
                u32 ra[4] = { vr0a.x, vr0a.y, vr0a.z, vr0a.w };
                u32 rb[4] = { vr0b.x, vr0b.y, vr0b.z, vr0b.w };
                int d0 = dch0*8;
#pragma unroll
                for (int k2 = 0; k2 < 4; k2++) {
                    u32 lo = (ra[k2] & 0xffffu) | (rb[k2] << 16);
                    u32 hi = (ra[k2] >> 16) | (rb[k2] & 0xffff0000u);
                    *(u32*)&vtn[(d0 + 2*k2)     * LV + ccv] = lo;
                    *(u32*)&vtn[(d0 + 2*k2 + 1) * LV + ccv] = hi;
                }
                u32 rc[4] = { vr1a.x, vr1a.y, vr1a.z, vr1a.w };
                u32 rd[4] = { vr1b.x, vr1b.y, vr1b.z, vr1b.w };
                d0 = dch1*8;
#pragma unroll
                for (int k2 = 0; k2 < 4; k2++) {
                    u32 lo = (rc[k2] & 0xffffu) | (rd[k2] << 16);
                    u32 hi = (rc[k2] >> 16) | (rd[k2] & 0xffff0000u);
                    *(u32*)&vtn[(d0 + 2*k2)     * LV + ccv] = lo;
                    *(u32*)&vtn[(d0 + 2*k2 + 1) * LV + ccv] = hi;
                }
            }
        }

        // ---- epilogue: O^T /= l (lane-local), pack, store b64 ----
        {
            float inv = 1.0f / lrun;
            size_t row = rowbase + qt*64 + w*16 + l15;
            u16* outp = AO + row * HIDDIM + h * HD + quad*4;
#pragma unroll
            for (int nt = 0; nt < 8; nt++) {
                uint2 o;
                o.x = (u32)f2bf(O[nt][0] * inv) | ((u32)f2bf(O[nt][1] * inv) << 16);
                o.y = (u32)f2bf(O[nt][2] * inv) | ((u32)f2bf(O[nt][3] * inv) << 16);
                *(uint2*)(outp + nt*16) = o;
            }
        }
    }
}

extern "C" void kernel_launch(void* const* d_in, const int* in_sizes, int n_in,
                              void* d_out, int out_size, void* d_ws, size_t ws_size,
                              hipStream_t stream) {
    (void)in_sizes; (void)n_in; (void)out_size; (void)ws_size;
    const float* x    = (const float*)d_in[0];
    const float* cosT = (const float*)d_in[1];
    const float* sinT = (const float*)d_in[2];
    const float* Wq   = (const float*)d_in[3];
    const float* Wk   = (const float*)d_in[4];
    const float* Wv   = (const float*)d_in[5];
    const float* Wo   = (const float*)d_in[6];

    char* ws = (char*)d_ws;
    u16* QKV   = (u16*)ws;                                             // 4096*3072 bf16
    u16* xb    = (u16*)(ws + (size_t)MROWS * NQKV * 2);                // 4096*2048 (then attn_out)
    u16* Wqkvt = (u16*)(ws + (size_t)MROWS * NQKV * 2 + (size_t)MROWS * HIDDIM * 2); // 3072*2048
    u16* Wot   = Wqkvt + (size_t)NQKV * KDIM;                          // 2048*2048

    prep_kernel<<<14336, 256, 0, stream>>>(x, xb, Wq, Wk, Wv, Wo, Wqkvt, Wot);
    gemm_bt<1><<<dim3(32, 24), 256, 0, stream>>>(xb, Wqkvt, QKV, NQKV);
    rotary_kernel<<<5120, 256, 0, stream>>>(QKV, cosT, sinT);
    attn_kernel<<<dim3(16, 16, 2), 256, 0, stream>>>(QKV, xb);
    gemm_bt<0><<<dim3(32, 16), 256, 0, stream>>>(xb, Wot, d_out, HIDDIM);
}